// Round 22
// baseline (685.385 us; speedup 1.0000x reference)
//
#include <hip/hip_runtime.h>

#define TT 2048
#define II 8
#define HH 24
#define THRESH 0.1f
#define LOG2E 1.4426950408889634f

typedef float v2f __attribute__((ext_vector_type(2)));

__device__ __forceinline__ float readlane_f(float v, int l) {
    return __int_as_float(__builtin_amdgcn_readlane(__float_as_int(v), l));
}

// FINAL (= R18 champion, 684 us, absmax 9.77e-4).
// One wave (= one block) per batch element; 2048 waves = 2 waves/SIMD.
//  lane l32=j<24, lo half : gate rows (i_j, f_j) — full 32-wide pk-dots
//  lane l32=j<24, hi half : gate rows (g_j, o_j)
//  lane 24                : PRED ROW — wA = [0(8); W_out(24)], biasA = b_out
//  lanes 25-28 / 57-60    : x lanes (k=0..3 / 4..7), per-step prefetch
//
// Structure ledger (what's in and why):
//  - per-lane x vector loads staged through LDS at the TAIL (R9): wave-
//    uniform x loads become s_load and poison lgkmcnt (R6/R8/R13);
//    register-carried x across phases diverges 4/4 times (R17/R19/R20/R21).
//  - head folded into lane-24's dot row (R16): kills the serial
//    permlane16+4xDPP tail; w0*v0 added post-fold (k=0 excluded).
//  - x8 unroll (R18): cross-step weight-load pipelining, -6%.
//  - once-per-gate nonlins via exp2+rcp, permlane32 distribution (R5).
//  - weights NOT loop-resident: 5 residency attempts all refused by RA;
//    the L1-hit reload tax is accepted.
__global__ __launch_bounds__(64)
__attribute__((amdgpu_waves_per_eu(2, 2)))
void lstm_anom_kernel(const float* __restrict__ x,
                      const float* __restrict__ W_ih,
                      const float* __restrict__ W_hh,
                      const float* __restrict__ b_ih,
                      const float* __restrict__ b_hh,
                      const float* __restrict__ W_out,
                      const float* __restrict__ b_out,
                      float* __restrict__ out)
{
    __shared__ __align__(16) float vbuf[32];   // [x0..x7; h0..h23]

    const int  lane  = threadIdx.x;
    const int  b     = blockIdx.x;
    const int  l32   = lane & 31;
    const bool hi    = lane >= 32;
    const int  jc    = (l32 < HH) ? l32 : 0;   // clamped for junk lanes
    const bool xLn   = (l32 >= 25 && l32 <= 28);   // 8 x lanes (both halves)
    const int  xk    = (l32 - 25) + (hi ? 4 : 0);  // 0..7

    const float* xb = x + (size_t)b * (TT * II);

    // ---- persistent weights: 2 full gate rows per lane ----
    const int rowA = (hi ? 2 * HH : 0) + jc;   // lo: i-gate, hi: g-gate
    const int rowB = rowA + HH;                // lo: f-gate, hi: o-gate
    float wAf[32], wBf[32];
    #pragma unroll
    for (int q = 0; q < 2; ++q) {
        const float4 qa = *(const float4*)(W_ih + rowA * II + q * 4);
        const float4 qb = *(const float4*)(W_ih + rowB * II + q * 4);
        wAf[q*4+0]=qa.x; wAf[q*4+1]=qa.y; wAf[q*4+2]=qa.z; wAf[q*4+3]=qa.w;
        wBf[q*4+0]=qb.x; wBf[q*4+1]=qb.y; wBf[q*4+2]=qb.z; wBf[q*4+3]=qb.w;
    }
    #pragma unroll
    for (int q = 0; q < 6; ++q) {
        const float4 qa = *(const float4*)(W_hh + rowA * HH + q * 4);
        const float4 qb = *(const float4*)(W_hh + rowB * HH + q * 4);
        wAf[8+q*4+0]=qa.x; wAf[8+q*4+1]=qa.y; wAf[8+q*4+2]=qa.z; wAf[8+q*4+3]=qa.w;
        wBf[8+q*4+0]=qb.x; wBf[8+q*4+1]=qb.y; wBf[8+q*4+2]=qb.z; wBf[8+q*4+3]=qb.w;
    }
    float biasA = b_ih[rowA] + b_hh[rowA];
    float biasB = b_ih[rowB] + b_hh[rowB];
    const float bout = b_out[0];
    // exclude k=0 from the stored dot; keep as separate scalar (added post-fold)
    float w0A = wAf[0], w0B = wBf[0];
    wAf[0] = 0.f; wBf[0] = 0.f;
    if (lane == 24) {                          // PRED row
        #pragma unroll
        for (int k = 0; k < 32; ++k) { wAf[k] = 0.f; wBf[k] = 0.f; }
        #pragma unroll
        for (int j = 0; j < HH; ++j) wAf[8 + j] = W_out[j];
        biasA = bout; biasB = 0.f; w0A = 0.f; w0B = 0.f;
    }
    v2f wA2[16], wB2[16];
    #pragma unroll
    for (int k = 0; k < 16; ++k) {
        wA2[k] = (v2f){ wAf[2*k], wAf[2*k+1] };
        wB2[k] = (v2f){ wBf[2*k], wBf[2*k+1] };
    }
    // nonlin A: lo -> sigmoid(a), hi -> tanh(a) = 2*sigmoid(2a)-1, uniform code
    const float kA = hi ? (-2.f * LOG2E) : (-LOG2E);
    const float mA = hi ? 2.f : 1.f;
    const float nA = hi ? -1.f : 0.f;

    // ---- init: vbuf = [x[b][0][:8]; h0 = 0]; x pipeline in x lanes ----
    if (lane < 32) vbuf[lane] = (lane < 8) ? xb[lane] : 0.f;
    float xA = 0.f, xB = 0.f;
    if (xLn) xA = xb[II + xk];                 // x[b][1][k], per-lane load
    __syncthreads();                           // once, before the loop

    v2f v2r[16];
    #pragma unroll
    for (int c8 = 0; c8 < 8; ++c8) {
        const float4 q = *(const float4*)&vbuf[c8 * 4];
        v2r[c8 * 2]     = (v2f){q.x, q.y};
        v2r[c8 * 2 + 1] = (v2f){q.z, q.w};
    }
    float cst = 0.f, predsave = 0.f;

    for (int t8 = 0; t8 < TT; t8 += 8) {
        #pragma unroll
        for (int s = 0; s < 8; ++s) {
            const int t = t8 + s;

            // ---- 2 full 32-wide gate dots per lane (k=0 excluded), pk-FMA ----
            v2f accA = (v2f){biasA, 0.f};
            v2f accB = (v2f){biasB, 0.f};
            #pragma unroll
            for (int k = 0; k < 16; ++k) {
                accA = __builtin_elementwise_fma(wA2[k], v2r[k], accA);
                accB = __builtin_elementwise_fma(wB2[k], v2r[k], accB);
            }
            float aA = accA.x + accA.y;
            float aB = accB.x + accB.y;

            // ---- pred(t-1) from lane 24's dot; anomaly select; w0 add ----
            const float x0    = v2r[0].x;                    // raw x[b][t][0]
            const float predR = readlane_f(aA, 24);
            const float predS = (t == 0) ? x0 : predR;       // pred0 = x0
            const float v0    = (fabsf(predS - x0) > THRESH) ? predS : x0;
            aA = fmaf(w0A, v0, aA);
            aB = fmaf(w0B, v0, aB);

            // ---- nonlinearities, once per gate ----
            const float sA = __builtin_amdgcn_rcpf(1.f + __builtin_amdgcn_exp2f(kA * aA));
            const float tA = fmaf(sA, mA, nA);               // lo: sig(i), hi: tanh(g)
            const float sB = __builtin_amdgcn_rcpf(1.f + __builtin_amdgcn_exp2f(-LOG2E * aB));
                                                             // lo: sig(f), hi: sig(o)
            // ---- distribute halves: every lane gets (ig,gg,fg,og) ----
            auto rA = __builtin_amdgcn_permlane32_swap(__float_as_int(tA), __float_as_int(tA), false, false);
            auto rB = __builtin_amdgcn_permlane32_swap(__float_as_int(sB), __float_as_int(sB), false, false);
            const float ig = __int_as_float(rA[0]);
            const float gg = __int_as_float(rA[1]);
            const float fg = __int_as_float(rB[0]);
            const float og = __int_as_float(rB[1]);

            cst = fmaf(fg, cst, ig * gg);
            const float sc = __builtin_amdgcn_rcpf(1.f + __builtin_amdgcn_exp2f(-2.f * LOG2E * cst));
            const float tc = fmaf(2.f, sc, -1.f);            // tanh(c)
            const float h  = og * tc;

            // ---- record pred(t-1); flush 64 at a time (coalesced 256B) ----
            predsave = (((t - 1) & 63) == lane) ? predS : predsave;
            if (t && (t & 63) == 0)
                out[(size_t)b * TT + (t - 64) + lane] = predsave;

            // ---- stage next step's inputs (banks distinct, conflict-free) ----
            if (lane < HH || xLn) vbuf[xLn ? xk : (8 + l32)] = xLn ? xA : h;
            if (xLn) {                           // per-lane VECTOR load (vmcnt)
                int tn = t + 2; if (tn > TT - 1) tn = TT - 1;
                xB = xb[(size_t)tn * II + xk];
            }

            // ---- reload v for next step (broadcast ds_read_b128, DS-only) ----
            #pragma unroll
            for (int c8 = 0; c8 < 8; ++c8) {
                const float4 q = *(const float4*)&vbuf[c8 * 4];
                v2r[c8 * 2]     = (v2f){q.x, q.y};
                v2r[c8 * 2 + 1] = (v2f){q.z, q.w};
            }
            if (xLn) xA = xB;
        }
    }

    // ---- epilogue: pred(TT-1) from h(TT-1) (in v2r now); final flush ----
    {
        v2f accA = (v2f){biasA, 0.f};
        #pragma unroll
        for (int k = 0; k < 16; ++k)
            accA = __builtin_elementwise_fma(wA2[k], v2r[k], accA);
        const float predL = readlane_f(accA.x + accA.y, 24);
        predsave = (lane == 63) ? predL : predsave;
        out[(size_t)b * TT + (TT - 64) + lane] = predsave;
    }
}

extern "C" void kernel_launch(void* const* d_in, const int* in_sizes, int n_in,
                              void* d_out, int out_size, void* d_ws, size_t ws_size,
                              hipStream_t stream) {
    const float* x     = (const float*)d_in[0];
    const float* W_ih  = (const float*)d_in[1];
    const float* W_hh  = (const float*)d_in[2];
    const float* b_ih  = (const float*)d_in[3];
    const float* b_hh  = (const float*)d_in[4];
    const float* W_out = (const float*)d_in[5];
    const float* b_out = (const float*)d_in[6];
    float* out = (float*)d_out;

    dim3 grid(2048);   // one wave per batch element
    dim3 block(64);
    lstm_anom_kernel<<<grid, block, 0, stream>>>(x, W_ih, W_hh, b_ih, b_hh,
                                                 W_out, b_out, out);
}